// Round 6
// baseline (520.901 us; speedup 1.0000x reference)
//
#include <hip/hip_runtime.h>

#define NN     200000
#define MPAD   200064   // 3126 * 64
#define NGRAPH 1024

typedef __bf16 bf16x8 __attribute__((ext_vector_type(8)));
typedef float  f32x4  __attribute__((ext_vector_type(4)));
typedef float  f32x2  __attribute__((ext_vector_type(2)));

// ---------- helpers ----------
__device__ __forceinline__ unsigned short f2bu(float f) {
    unsigned u = __float_as_uint(f);
    unsigned r = (u + 0x7FFFu + ((u >> 16) & 1u)) >> 16;
    return (unsigned short)r;
}
__device__ __forceinline__ float b2f(unsigned short u) {
    return __uint_as_float(((unsigned)u) << 16);
}
__device__ __forceinline__ unsigned cvt_pk(float lo, float hi) {
    // RNE, bit-identical to f2bu for finite inputs
    unsigned r;
    asm("v_cvt_pk_bf16_f32 %0, %1, %2" : "=v"(r) : "v"(lo), "v"(hi));
    return r;
}

// ---------- kernel 1: weight prep ----------
// wcatT[n][k] = [Wg1|Wn1][k][n] bf16.
// wfragT: 8 slices x 64 lanes x 8 bf16 — B-fragments for the fused alpha
// MFMA (see gemm_fused). hi rows + lo-residual rows = fp32-accurate Wg2.
__global__ __launch_bounds__(256) void convert_w(
    const float* __restrict__ Wg1, const float* __restrict__ Wn1,
    const float* __restrict__ Wg2,
    unsigned short* __restrict__ wcatT, unsigned short* __restrict__ wfragT) {
    int i = blockIdx.x * 256 + threadIdx.x;
    if (i < 512 * 256) {
        int n = i >> 8, k = i & 255;
        float v = (n < 256) ? Wg1[k * 256 + n] : Wn1[k * 256 + (n - 256)];
        wcatT[i] = f2bu(v);
    } else if (i < 512 * 256 + 4096) {
        int j = i - 512 * 256;
        int e = j & 7, l = (j >> 3) & 63, s = j >> 9;
        int quad = l >> 4, c = l & 15;
        int n = (s >> 2) * 128 + ((s >> 1) & 1) * 64 + (s & 1) * 32
              + ((e >> 2) * 16) + quad * 4 + (e & 3);
        float w = Wg2[n * 8 + (c & 7)];
        unsigned short hi = f2bu(w);
        wfragT[j] = (c < 8) ? hi : f2bu(w - b2f(hi));
    }
}

// ---------- kernel 2: fused GEMM + alpha ----------
// h_n = relu(x@Wn1 + bn1)  -> C [MPAD,256] bf16   (col-tiles ct=2,3)
// alpha = relu(x@Wg1)@Wg2  -> alpha [NN,8] f32    (col-tiles ct=0,1, fused)
// Round-6 structure: NO barriers in the K-loop. B (256 KB, L2-resident)
// is read global->register with an explicit 2-deep register double-buffer
// (bfr[2][4], next kk-step's loads issued before the current 8-MFMA
// cluster). Rounds 2/4/5 proved any __syncthreads in the K-loop drains
// vmcnt(0) and exposes the full L2 latency regardless of LDS staging
// arrangement; round 3's direct-load regression was zero prefetch + only
// 2 waves/SIMD. Dropping Bs shrinks LDS to 34 KB -> 4 blocks/CU
// (4 waves/SIMD); barrier-free waves desync and cover each other.
__global__ __launch_bounds__(256, 4) void gemm_fused(
    const float* __restrict__ x,              // [NN,256] f32
    const unsigned short* __restrict__ Bt,    // wcatT [512,256] bf16
    const float* __restrict__ bn1,            // [256]
    const unsigned short* __restrict__ wfragT,// [8*64*8] bf16
    unsigned short* __restrict__ C,           // h_n [MPAD,256] bf16
    float* __restrict__ alpha) {              // [NN,8] f32
    __shared__ unsigned short As[64 * 256];   // 32 KB
    __shared__ float redA[64 * 8];            // 2 KB (alpha cross-wave red)
    const int tid  = threadIdx.x;
    const int lane = tid & 63;
    const int wave = tid >> 6;
    const int wm = wave >> 1, wn = wave & 1;
    const size_t m0 = (size_t)blockIdx.x * 64;
    const int frow = lane & 15;
    const int quad = lane >> 4;

    // ---- stage A panel (64 rows): f32 x -> bf16, chunk c -> slot c^(r&7)
    {
        const int lane4 = lane * 4;
        const int c = lane4 >> 3;
        #pragma unroll 1
        for (int p2 = 0; p2 < 2; ++p2) {
            float4 v[8];
            #pragma unroll
            for (int q = 0; q < 8; ++q) {
                int row = (p2 * 8 + q) * 4 + wave;
                size_t gr = m0 + row;
                if (gr > (size_t)(NN - 1)) gr = NN - 1;   // clamp pad rows
                v[q] = *(const float4*)(x + gr * 256 + lane4);
            }
            #pragma unroll
            for (int q = 0; q < 8; ++q) {
                int row = (p2 * 8 + q) * 4 + wave;
                unsigned u0 = cvt_pk(v[q].x, v[q].y);
                unsigned u1 = cvt_pk(v[q].z, v[q].w);
                int off = row * 256 + ((c ^ (row & 7)) << 3) + (lane4 & 7);
                uint2 w; w.x = u0; w.y = u1;
                *(uint2*)(As + off) = w;          // 8B, aligned
            }
        }
    }

    // ---- B fragment loader: unit u = ct*8 + k8 -> 4 x 16B direct loads.
    // Per lane: rows (u>>3)*128 + wn*64 + j*16 + frow, k = (u&7)*32 + quad*8.
    const unsigned short* Bbase = Bt + (size_t)(wn * 64 + frow) * 256 + quad * 8;

    bf16x8 bfr[2][4];
    {   // prologue: load unit 0 into set 0
        const unsigned short* p = Bbase;    // n0=0, k8=0
        #pragma unroll
        for (int j = 0; j < 4; ++j)
            bfr[0][j] = *(const bf16x8*)(p + j * 16 * 256);
    }
    __syncthreads();   // A panel ready (also drains prologue B loads)

    f32x4 aacc[2] = {};   // alpha accumulator (persists over ct=0,1)

    #pragma unroll 1
    for (int ct = 0; ct < 4; ++ct) {
        f32x4 acc[2][4] = {};
        #pragma unroll
        for (int k8 = 0; k8 < 8; ++k8) {
            const int u  = ct * 8 + k8;
            const int cb = k8 & 1, nb = cb ^ 1;
            if (u + 1 < 32) {   // prefetch next unit into the other set
                const int nu = u + 1;
                const unsigned short* p = Bbase
                    + (size_t)((nu >> 3) * 128) * 256 + (nu & 7) * 32;
                #pragma unroll
                for (int j = 0; j < 4; ++j)
                    bfr[nb][j] = *(const bf16x8*)(p + j * 16 * 256);
            }
            const int sa = (k8 * 4 + quad) ^ (frow & 7);
            bf16x8 af[2];
            #pragma unroll
            for (int i = 0; i < 2; ++i)
                af[i] = *(const bf16x8*)(As + (wm * 32 + i * 16 + frow) * 256 + sa * 8);
            #pragma unroll
            for (int i = 0; i < 2; ++i)
                #pragma unroll
                for (int j = 0; j < 4; ++j)
                    acc[i][j] = __builtin_amdgcn_mfma_f32_16x16x32_bf16(
                        bfr[cb][j], af[i], acc[i][j], 0, 0, 0);   // SWAPPED
        }

        if (ct < 2) {
            // ---- fused alpha: relu(acc) is an A-fragment (row=frow=node,
            // k-slot(quad,e)=col per wfragT's permutation); 2 j-pairs -> K=32.
            #pragma unroll
            for (int p = 0; p < 2; ++p) {
                bf16x8 wf = *(const bf16x8*)(
                    wfragT + (((ct << 2) + (wn << 1) + p) * 64 + lane) * 8);
                #pragma unroll
                for (int i = 0; i < 2; ++i) {
                    f32x4 v0 = acc[i][2 * p], v1 = acc[i][2 * p + 1];
                    unsigned u0 = cvt_pk(fmaxf(v0[0], 0.f), fmaxf(v0[1], 0.f));
                    unsigned u1 = cvt_pk(fmaxf(v0[2], 0.f), fmaxf(v0[3], 0.f));
                    unsigned u2 = cvt_pk(fmaxf(v1[0], 0.f), fmaxf(v1[1], 0.f));
                    unsigned u3 = cvt_pk(fmaxf(v1[2], 0.f), fmaxf(v1[3], 0.f));
                    union { unsigned u[4]; bf16x8 b; } a8 = {{u0, u1, u2, u3}};
                    aacc[i] = __builtin_amdgcn_mfma_f32_16x16x32_bf16(
                        a8.b, wf, aacc[i], 0, 0, 0);
                }
            }
            if (ct == 1) {
                // finalize alpha: fold hi+lo residual, reduce across wn
                // halves through redA, write global.
                #pragma unroll
                for (int i = 0; i < 2; ++i)
                    #pragma unroll
                    for (int r = 0; r < 4; ++r)
                        aacc[i][r] += __shfl_xor(aacc[i][r], 8);
                if (wn == 0 && frow < 8) {
                    #pragma unroll
                    for (int i = 0; i < 2; ++i)
                        #pragma unroll
                        for (int r = 0; r < 4; ++r)
                            redA[(wm * 32 + i * 16 + quad * 4 + r) * 8 + frow] = aacc[i][r];
                }
                __syncthreads();
                if (wn == 1 && frow < 8) {
                    #pragma unroll
                    for (int i = 0; i < 2; ++i)
                        #pragma unroll
                        for (int r = 0; r < 4; ++r) {
                            int ml = wm * 32 + i * 16 + quad * 4 + r;
                            size_t m = m0 + ml;
                            if (m < NN)
                                alpha[m * 8 + frow] = redA[ml * 8 + frow] + aacc[i][r];
                        }
                }
            }
        } else {
            // ---- h_n epilogue: bias (vector add along reg axis), relu,
            // pack 4 bf16 -> one 8B store per (i,j).
            #pragma unroll
            for (int j = 0; j < 4; ++j) {
                f32x4 bv = *(const f32x4*)(bn1 + (ct - 2) * 128 + wn * 64 + j * 16 + quad * 4);
                #pragma unroll
                for (int i = 0; i < 2; ++i) {
                    f32x4 v = acc[i][j] + bv;
                    unsigned u0 = cvt_pk(fmaxf(v[0], 0.f), fmaxf(v[1], 0.f));
                    unsigned u1 = cvt_pk(fmaxf(v[2], 0.f), fmaxf(v[3], 0.f));
                    uint2 w; w.x = u0; w.y = u1;
                    size_t row = m0 + wm * 32 + i * 16 + frow;
                    *(uint2*)(C + row * 256 + (ct - 2) * 128 + wn * 64 + j * 16 + quad * 4) = w;
                }
            }
        }
    }
}

// ---------- kernel 3: softmax + gated segment-sum + tiny GEMV ----------
__device__ __forceinline__ int lower_bound(const int* __restrict__ b, int key) {
    int lo = 0, hi = NN;
    while (lo < hi) { int mid = (lo + hi) >> 1; if (b[mid] < key) lo = mid + 1; else hi = mid; }
    return lo;
}

#define GST 9   // padded head-stride for G partials (bank-conflict-free)

__global__ __launch_bounds__(256) void pool2(
    const float* __restrict__ alpha, const unsigned short* __restrict__ h,
    const float* __restrict__ Wn2, const float* __restrict__ bn2,
    const int* __restrict__ batch, float* __restrict__ out) {
    __shared__ float red[256];
    __shared__ float mh[8], ih[8];
    __shared__ float gate_s[64][8];       // 2 KB (zero-padded past cn)
    __shared__ float Gs4[4][256 * GST];   // 36 KB group partials
    const int g = blockIdx.x, t = threadIdx.x;
    const int start = lower_bound(batch, g);
    const int end   = lower_bound(batch, g + 1);
    const int hd = t & 7;

    float mloc = -INFINITY;
    for (int n = start + (t >> 3); n < end; n += 32)
        mloc = fmaxf(mloc, alpha[n * 8 + hd]);
    red[t] = mloc; __syncthreads();
    for (int off = 128; off >= 8; off >>= 1) {
        if (t < off) red[t] = fmaxf(red[t], red[t + off]);
        __syncthreads();
    }
    if (t < 8) mh[t] = red[t];
    __syncthreads();
    const float mm = mh[hd];

    float sloc = 0.f;
    for (int n = start + (t >> 3); n < end; n += 32)
        sloc += __expf(alpha[n * 8 + hd] - mm);
    red[t] = sloc; __syncthreads();
    for (int off = 128; off >= 8; off >>= 1) {
        if (t < off) red[t] += red[t + off];
        __syncthreads();
    }
    if (t < 8) ih[t] = 1.0f / (red[t] + 1e-16f);
    __syncthreads();

    // pass 3: G[k, 0..7] += gate[n,:] * h_n[n, k]
    // 4 node-groups x 64 threads; thread owns cols c4..c4+3 via one 8B
    // ushort4 load per node. Gate rows zero-padded so the j-loop trip
    // count is a static 16 (#pragma unroll 4 -> loads pipelined).
    const int grp = t >> 6;
    const int c4  = (t & 63) * 4;
    f32x2 G[4][4] = {};                   // [col d][head pair i]
    for (int c0 = start; c0 < end; c0 += 64) {
        const int cn = min(64, end - c0);
        __syncthreads();
        #pragma unroll
        for (int u2 = 0; u2 < 2; ++u2) {
            int u = t + u2 * 256;
            int j = u >> 3, hh = u & 7;
            gate_s[j][hh] = (j < cn)
                ? __expf(alpha[(size_t)(c0 + j) * 8 + hh] - mh[hh]) * ih[hh]
                : 0.0f;
        }
        __syncthreads();
        const int j0 = grp * 16;
        #pragma unroll 4
        for (int jj = 0; jj < 16; ++jj) {
            const int j = j0 + jj;
            // c0+j < NN+64 <= MPAD: pad rows hold finite data, gate=0
            ushort4 hv = *(const ushort4*)(h + (size_t)(c0 + j) * 256 + c4);
            const f32x2* gp = (const f32x2*)&gate_s[j][0];   // LDS broadcast
            const f32x2 g0 = gp[0], g1 = gp[1], g2 = gp[2], g3 = gp[3];
            f32x2 v;
            v = {b2f(hv.x), b2f(hv.x)};
            G[0][0] += g0 * v; G[0][1] += g1 * v; G[0][2] += g2 * v; G[0][3] += g3 * v;
            v = {b2f(hv.y), b2f(hv.y)};
            G[1][0] += g0 * v; G[1][1] += g1 * v; G[1][2] += g2 * v; G[1][3] += g3 * v;
            v = {b2f(hv.z), b2f(hv.z)};
            G[2][0] += g0 * v; G[2][1] += g1 * v; G[2][2] += g2 * v; G[2][3] += g3 * v;
            v = {b2f(hv.w), b2f(hv.w)};
            G[3][0] += g0 * v; G[3][1] += g1 * v; G[3][2] += g2 * v; G[3][3] += g3 * v;
        }
    }
    __syncthreads();
    // write group partials (once per block; GST=9 spreads banks)
    #pragma unroll
    for (int d = 0; d < 4; ++d)
        #pragma unroll
        for (int i = 0; i < 4; ++i) {
            Gs4[grp][(c4 + d) * GST + 2 * i]     = G[d][i][0];
            Gs4[grp][(c4 + d) * GST + 2 * i + 1] = G[d][i][1];
        }
    __syncthreads();
    // reduce 4 groups -> Gs4[0]; thread t owns row k=t (9t%32 bijective)
    {
        float* Gf = &Gs4[0][0];
        #pragma unroll
        for (int e = 0; e < 8; ++e) {
            int idx = t * GST + e;
            Gf[idx] = Gf[idx] + Gf[256 * GST + idx]
                    + Gf[512 * GST + idx] + Gf[768 * GST + idx];
        }
    }
    __syncthreads();

    float acc = 0.f;
    #pragma unroll 4
    for (int k = 0; k < 256; ++k)
        acc += Gs4[0][k * GST + hd] * Wn2[k * 256 + t];
    const float sg = (end > start) ? 1.0f : 0.0f;
    out[g * 256 + t] = acc + sg * bn2[t];
}

// ---------- launch ----------
extern "C" void kernel_launch(void* const* d_in, const int* in_sizes, int n_in,
                              void* d_out, int out_size, void* d_ws, size_t ws_size,
                              hipStream_t stream) {
    const float* x     = (const float*)d_in[0];
    const int*   batch = (const int*)d_in[1];
    const float* Wg1   = (const float*)d_in[2];
    const float* Wg2   = (const float*)d_in[3];
    const float* Wn1   = (const float*)d_in[4];
    const float* bn1   = (const float*)d_in[5];
    const float* Wn2   = (const float*)d_in[6];
    const float* bn2   = (const float*)d_in[7];
    float* out = (float*)d_out;

    unsigned short* h      = (unsigned short*)d_ws;           // MPAD*256 (h_n only)
    unsigned short* wcatT  = h + (size_t)MPAD * 256;          // 512*256
    unsigned short* wfragT = wcatT + 512 * 256;               // 8*64*8
    float* alpha = (float*)(wfragT + 4096);                   // NN*8

    convert_w<<<528, 256, 0, stream>>>(Wg1, Wn1, Wg2, wcatT, wfragT);
    gemm_fused<<<3126, 256, 0, stream>>>(x, wcatT, bn1, wfragT, h, alpha);
    pool2<<<NGRAPH, 256, 0, stream>>>(alpha, h, Wn2, bn2, batch, out);
}